// Round 6
// baseline (542.260 us; speedup 1.0000x reference)
//
#include <hip/hip_runtime.h>
#include <math.h>

#define C1F 1.0e-4f   // 0.01^2
#define C2F 9.0e-4f   // 0.03^2
#define TX 32
#define TY 8

// acc layout: per scale i (0..3), base = i*8
//  +0: sum |left_est - lpy|      +1: sum |right_est - rpy|
//  +2: sum |rl_disp - dl|        +3: sum |lr_disp - dr|
//  +4: sum x-grad smooth (dl+dr) +5: sum y-grad smooth (dl+dr)
//  +6: sum ssim_l (clipped)      +7: sum ssim_r

struct ScaleArgs {
    const float* disp;
    int h, w, nx, ny, blk0;
};

__device__ __forceinline__ float2 f2(float v) { return make_float2(v, v); }
__device__ __forceinline__ float2 f2abs(float2 a) {
    return make_float2(fabsf(a.x), fabsf(a.y));
}

__device__ __forceinline__ void warp_coeffs(float px, int W, int& i0, int& i1,
                                            float& w0, float& w1) {
    float x0f = floorf(px);
    float f = px - x0f;
    int x0i = (int)x0f;
    int x1i = x0i + 1;
    float v0 = (x0i >= 0 && x0i < W) ? 1.f : 0.f;
    float v1 = (x1i >= 0 && x1i < W) ? 1.f : 0.f;
    i0 = min(max(x0i, 0), W - 1);
    i1 = min(max(x1i, 0), W - 1);
    w0 = v0 * (1.f - f);
    w1 = v1 * f;
}

// Bilinear align-corners sample of full-res img (3 channels at once), exactly
// replicating the reference resize arithmetic. y-part (y0,y1,wy) precomputed.
__device__ __forceinline__ float3 bil3(const float* __restrict__ img,
                                       long long bOff, long long cStride,
                                       int FW, int y0, int y1, float wy,
                                       int xs, float sx) {
    float fx = (float)xs * sx;
    int x0 = (int)floorf(fx);
    float wx = fx - (float)x0;
    int x1 = min(x0 + 1, FW - 1);
    x0 = min(x0, FW - 1);
    const float* p0 = img + bOff + (long long)y0 * FW;
    const float* p1 = img + bOff + (long long)y1 * FW;
    float3 r;
    {
        float a00 = p0[x0], a10 = p1[x0], a01 = p0[x1], a11 = p1[x1];
        float r0 = a00 * (1.f - wy) + a10 * wy;
        float r1 = a01 * (1.f - wy) + a11 * wy;
        r.x = r0 * (1.f - wx) + r1 * wx;
    }
    p0 += cStride; p1 += cStride;
    {
        float a00 = p0[x0], a10 = p1[x0], a01 = p0[x1], a11 = p1[x1];
        float r0 = a00 * (1.f - wy) + a10 * wy;
        float r1 = a01 * (1.f - wy) + a11 * wy;
        r.y = r0 * (1.f - wx) + r1 * wx;
    }
    p0 += cStride; p1 += cStride;
    {
        float a00 = p0[x0], a10 = p1[x0], a01 = p0[x1], a11 = p1[x1];
        float r0 = a00 * (1.f - wy) + a10 * wy;
        float r1 = a01 * (1.f - wy) + a11 * wy;
        r.z = r0 * (1.f - wx) + r1 * wx;
    }
    return r;
}

template<int N>
__device__ __forceinline__ void block_acc(const float* vals, float* gacc) {
    __shared__ float sacc[N];
    if (threadIdx.x < N) sacc[threadIdx.x] = 0.f;
    __syncthreads();
#pragma unroll
    for (int k = 0; k < N; ++k) {
        float v = vals[k];
#pragma unroll
        for (int off = 32; off > 0; off >>= 1) v += __shfl_down(v, off, 64);
        if ((threadIdx.x & 63) == 0) atomicAdd(&sacc[k], v);
    }
    __syncthreads();
    if (threadIdx.x < N) atomicAdd(&gacc[threadIdx.x], sacc[threadIdx.x]);
}

__global__ void k_zero(float* acc) {
    if (threadIdx.x < 64) acc[threadIdx.x] = 0.f;
}

// Fully fused loss kernel: all 4 scales, resize composed inline (no pyramid
// materialization). Scale 0 (75% of blocks) uses the direct-load staging path;
// scales 1-3 compose resize+warp with bit-identical fp expressions.
__global__ void __launch_bounds__(256, 4)
k_fused_all(ScaleArgs s0, ScaleArgs s1, ScaleArgs s2, ScaleArgs s3,
            const float* __restrict__ fleft, const float* __restrict__ fright,
            int FH, int FW, float* __restrict__ accbase) {
    __shared__ float4 simg[3][(TY + 2) * (TX + 2)];
    __shared__ float2 sdisp[(TY + 2) * (TX + 2)];

    ScaleArgs sa;
    int scale;
    {
        int blk = blockIdx.x;
        if (blk >= s3.blk0)      { sa = s3; scale = 3; }
        else if (blk >= s2.blk0) { sa = s2; scale = 2; }
        else if (blk >= s1.blk0) { sa = s1; scale = 1; }
        else                     { sa = s0; scale = 0; }
    }
    const int h = sa.h, w = sa.w;
    const float* __restrict__ disp = sa.disp;
    float* acc = accbase + scale * 8;

    int t = blockIdx.x - sa.blk0;
    const int tileX = t % sa.nx;
    int t2 = t / sa.nx;
    const int tileY = t2 % sa.ny;
    const int b = t2 / sa.ny;

    const int xo0 = tileX * TX;
    const int yo0 = tileY * TY;
    const int tid = threadIdx.x;
    const float Wm1 = (float)(w - 1);
    const float invWm1 = 1.f / Wm1;

    const float* dl_base = disp + ((long long)b * 2 + 0) * h * w;
    const float* dr_base = disp + ((long long)b * 2 + 1) * h * w;
    const long long cStride = (long long)FH * FW;
    const long long bOff = (long long)b * 3 * cStride;

    // ---- staging ----
    for (int i = tid; i < (TY + 2) * (TX + 2); i += 256) {
        int sx_ = i % (TX + 2);
        int sy_ = i / (TX + 2);
        int x = min(max(xo0 - 1 + sx_, 0), w - 1);
        int y = min(max(yo0 - 1 + sy_, 0), h - 1);
        const float* dl_row = dl_base + (long long)y * w;
        const float* dr_row = dr_base + (long long)y * w;
        float dl = dl_row[x], dr = dr_row[x];
        sdisp[i] = make_float2(dl, dr);
        float xb = (float)x * invWm1;
        int i0L, i1L; float w0L, w1L;
        warp_coeffs((xb - dl) * Wm1, w, i0L, i1L, w0L, w1L);
        int i0R, i1R; float w0R, w1R;
        warp_coeffs((xb + dr) * Wm1, w, i0R, i1R, w0R, w1R);
        if (scale == 0) {
#pragma unroll
            for (int c = 0; c < 3; ++c) {
                const float* lrow = fleft + bOff + c * cStride + (long long)y * FW;
                const float* rrow = fright + bOff + c * cStride + (long long)y * FW;
                float lv = lrow[x], rv = rrow[x];
                float le = rrow[i0L] * w0L + rrow[i1L] * w1L;
                float re = lrow[i0R] * w0R + lrow[i1R] * w1R;
                simg[c][i] = make_float4(le, re, lv, rv);
            }
        } else {
            // compose: pyramid pixel = bilinear(full-res), exact resize math
            float syc = (float)(FH - 1) / (float)(h - 1);
            float sxc = (float)(FW - 1) / (float)(w - 1);
            float fy = (float)y * syc;
            int y0 = (int)floorf(fy);
            float wy = fy - (float)y0;
            int y1 = min(y0 + 1, FH - 1);
            y0 = min(y0, FH - 1);
            float3 lv3 = bil3(fleft, bOff, cStride, FW, y0, y1, wy, x, sxc);
            float3 rv3 = bil3(fright, bOff, cStride, FW, y0, y1, wy, x, sxc);
            float3 rg0 = bil3(fright, bOff, cStride, FW, y0, y1, wy, i0L, sxc);
            float3 rg1 = bil3(fright, bOff, cStride, FW, y0, y1, wy, i1L, sxc);
            float3 lg0 = bil3(fleft, bOff, cStride, FW, y0, y1, wy, i0R, sxc);
            float3 lg1 = bil3(fleft, bOff, cStride, FW, y0, y1, wy, i1R, sxc);
            simg[0][i] = make_float4(rg0.x * w0L + rg1.x * w1L,
                                     lg0.x * w0R + lg1.x * w1R, lv3.x, rv3.x);
            simg[1][i] = make_float4(rg0.y * w0L + rg1.y * w1L,
                                     lg0.y * w0R + lg1.y * w1R, lv3.y, rv3.y);
            simg[2][i] = make_float4(rg0.z * w0L + rg1.z * w1L,
                                     lg0.z * w0R + lg1.z * w1R, lv3.z, rv3.z);
        }
    }
    __syncthreads();

    float sums[8] = {0.f, 0.f, 0.f, 0.f, 0.f, 0.f, 0.f, 0.f};
    const int tx = tid % TX, ty = tid / TX;
    const int x = xo0 + tx, y = yo0 + ty;
    if (x < w && y < h) {
        const int s = (ty + 1) * (TX + 2) + (tx + 1);   // own pixel's slot
        float2 dd = sdisp[s];
        float dl = dd.x, dr = dd.y;
        // L1 photometric (packed)
#pragma unroll
        for (int c = 0; c < 3; ++c) {
            float4 v = simg[c][s];
            float2 a = make_float2(v.x, v.y);   // (le, re)
            float2 bb = make_float2(v.z, v.w);  // (lv, rv)
            float2 d = f2abs(a - bb);
            sums[0] += d.x;
            sums[1] += d.y;
        }
        // LR consistency (far gathers on disp rows -> global)
        {
            float xb = (float)x * invWm1;
            int i0, i1; float w0, w1;
            warp_coeffs((xb - dl) * Wm1, w, i0, i1, w0, w1);
            const float* dr_row = dr_base + (long long)y * w;
            float rl = dr_row[i0] * w0 + dr_row[i1] * w1;
            sums[2] += fabsf(rl - dl);
            warp_coeffs((xb + dr) * Wm1, w, i0, i1, w0, w1);
            const float* dl_row = dl_base + (long long)y * w;
            float lr = dl_row[i0] * w0 + dl_row[i1] * w1;
            sums[3] += fabsf(lr - dr);
        }
        // edge-aware smoothness (neighbors from LDS)
        const float third = 1.f / 3.f;
        if (x < w - 1) {
            float2 d1 = sdisp[s + 1];
            float2 alr = f2(0.f);
#pragma unroll
            for (int c = 0; c < 3; ++c) {
                float4 v = simg[c][s];
                float4 v1 = simg[c][s + 1];
                alr = alr + f2abs(make_float2(v.z, v.w) - make_float2(v1.z, v1.w));
            }
            sums[4] += fabsf((dl - d1.x) * expf(-alr.x * third)) +
                       fabsf((dr - d1.y) * expf(-alr.y * third));
        }
        if (y < h - 1) {
            float2 d1 = sdisp[s + (TX + 2)];
            float2 alr = f2(0.f);
#pragma unroll
            for (int c = 0; c < 3; ++c) {
                float4 v = simg[c][s];
                float4 v1 = simg[c][s + (TX + 2)];
                alr = alr + f2abs(make_float2(v.z, v.w) - make_float2(v1.z, v1.w));
            }
            sums[5] += fabsf((dl - d1.x) * expf(-alr.x * third)) +
                       fabsf((dr - d1.y) * expf(-alr.y * third));
        }
        // SSIM (packed L/R in float2 lanes)
        if (x >= 1 && x <= w - 2 && y >= 1 && y <= h - 2) {
            const float2 inv9 = f2(1.f / 9.f);
            const float2 c1 = f2(C1F), c2 = f2(C2F);
            const float2 two = f2(2.f), one = f2(1.f), half_ = f2(0.5f);
#pragma unroll 1
            for (int c = 0; c < 3; ++c) {
                float2 sX = f2(0.f), sY = f2(0.f);
                float2 sXX = f2(0.f), sYY = f2(0.f), sXY = f2(0.f);
#pragma unroll
                for (int dy = 0; dy < 3; ++dy) {
#pragma unroll
                    for (int dx = 0; dx < 3; ++dx) {
                        float4 v = simg[c][(ty + dy) * (TX + 2) + (tx + dx)];
                        float2 a = make_float2(v.x, v.y);
                        float2 bb = make_float2(v.z, v.w);
                        sX = sX + a;
                        sY = sY + bb;
                        sXX = sXX + a * a;
                        sYY = sYY + bb * bb;
                        sXY = sXY + a * bb;
                    }
                }
                float2 mx = sX * inv9, my = sY * inv9;
                float2 vx = sXX * inv9 - mx * mx;
                float2 vy = sYY * inv9 - my * my;
                float2 vxy = sXY * inv9 - mx * my;
                float2 num = (two * mx * my + c1) * (two * vxy + c2);
                float2 den = (mx * mx + my * my + c1) * (vx + vy + c2);
                float2 ss = make_float2(num.x / den.x, num.y / den.y);
                float2 v = (one - ss) * half_;
                sums[6] += fminf(fmaxf(v.x, 0.f), 1.f);
                sums[7] += fminf(fmaxf(v.y, 0.f), 1.f);
            }
        }
    }
    block_acc<8>(sums, acc);
}

__global__ void k_final(const float* __restrict__ acc, float* __restrict__ out,
                        int B, int H, int W) {
    if (threadIdx.x != 0 || blockIdx.x != 0) return;
    float img = 0.f, lr = 0.f, sm = 0.f;
    for (int i = 0; i < 4; ++i) {
        int r = 1 << i;
        int h = H / r, w = W / r;
        const float* a = acc + i * 8;
        float Nl1 = (float)B * 3.f * (float)h * (float)w;
        float Nss = (float)B * 3.f * (float)(h - 2) * (float)(w - 2);
        float Nlr = (float)B * (float)h * (float)w;
        float Nsx = (float)B * (float)h * (float)(w - 1);
        float Nsy = (float)B * (float)(h - 1) * (float)w;
        img += 0.5f * (a[6] / Nss) + 0.5f * (a[0] / Nl1)
             + 0.5f * (a[7] / Nss) + 0.5f * (a[1] / Nl1);
        lr += a[2] / Nlr + a[3] / Nlr;
        sm += (a[4] / Nsx + a[5] / Nsy) / (float)r;
    }
    out[0] = img + 0.1f * sm + 1.0f * lr;
}

extern "C" void kernel_launch(void* const* d_in, const int* in_sizes, int n_in,
                              void* d_out, int out_size, void* d_ws, size_t ws_size,
                              hipStream_t stream) {
    const int B = 16, H = 384, W = 768;
    const float* disp[4] = {(const float*)d_in[0], (const float*)d_in[1],
                            (const float*)d_in[2], (const float*)d_in[3]};
    const float* left = (const float*)d_in[4];
    const float* right = (const float*)d_in[5];
    float* out = (float*)d_out;
    float* acc = (float*)d_ws;

    const int TB = 256;
    hipLaunchKernelGGL(k_zero, dim3(1), dim3(64), 0, stream, acc);

    {
        ScaleArgs sa[4];
        int blk0 = 0;
        for (int i = 0; i < 4; ++i) {
            int r = 1 << i;
            int h = H / r, w = W / r;
            sa[i].disp = disp[i];
            sa[i].h = h;
            sa[i].w = w;
            sa[i].nx = w / TX;
            sa[i].ny = h / TY;
            sa[i].blk0 = blk0;
            blk0 += sa[i].nx * sa[i].ny * B;
        }
        hipLaunchKernelGGL(k_fused_all, dim3((unsigned)blk0), dim3(TB), 0, stream,
                           sa[0], sa[1], sa[2], sa[3], left, right, H, W, acc);
    }
    hipLaunchKernelGGL(k_final, dim3(1), dim3(64), 0, stream, acc, out, B, H, W);
}

// Round 7
// 513.973 us; speedup vs baseline: 1.0550x; 1.0550x over previous
//
#include <hip/hip_runtime.h>
#include <math.h>

#define C1F 1.0e-4f   // 0.01^2
#define C2F 9.0e-4f   // 0.03^2
#define TX 32
#define TY 8

// acc layout: per scale i (0..3), base = i*8
//  +0: sum |left_est - lpy|      +1: sum |right_est - rpy|
//  +2: sum |rl_disp - dl|        +3: sum |lr_disp - dr|
//  +4: sum x-grad smooth (dl+dr) +5: sum y-grad smooth (dl+dr)
//  +6: sum ssim_l (clipped)      +7: sum ssim_r

struct ScaleArgs {
    const float* disp;
    const float* lp;
    const float* rp;
    int h, w, nx, ny, blk0, accoff;
};

__device__ __forceinline__ float2 f2(float v) { return make_float2(v, v); }
__device__ __forceinline__ float2 f2abs(float2 a) {
    return make_float2(fabsf(a.x), fabsf(a.y));
}

__device__ __forceinline__ void warp_coeffs(float px, int W, int& i0, int& i1,
                                            float& w0, float& w1) {
    float x0f = floorf(px);
    float f = px - x0f;
    int x0i = (int)x0f;
    int x1i = x0i + 1;
    float v0 = (x0i >= 0 && x0i < W) ? 1.f : 0.f;
    float v1 = (x1i >= 0 && x1i < W) ? 1.f : 0.f;
    i0 = min(max(x0i, 0), W - 1);
    i1 = min(max(x1i, 0), W - 1);
    w0 = v0 * (1.f - f);
    w1 = v1 * f;
}

template<int N>
__device__ __forceinline__ void block_acc(const float* vals, float* gacc) {
    __shared__ float sacc[N];
    if (threadIdx.x < N) sacc[threadIdx.x] = 0.f;
    __syncthreads();
#pragma unroll
    for (int k = 0; k < N; ++k) {
        float v = vals[k];
#pragma unroll
        for (int off = 32; off > 0; off >>= 1) v += __shfl_down(v, off, 64);
        if ((threadIdx.x & 63) == 0) atomicAdd(&sacc[k], v);
    }
    __syncthreads();
    if (threadIdx.x < N) atomicAdd(&gacc[threadIdx.x], sacc[threadIdx.x]);
}

__global__ void k_zero(float* acc) {
    if (threadIdx.x < 64) acc[threadIdx.x] = 0.f;
}

// ---- fused loss tile (R5-proven body), shared by kernels A and B ----
__device__ __forceinline__ void fused_tile(const ScaleArgs& sa, int t,
                                           float* __restrict__ accbase) {
    __shared__ float4 simg[3][(TY + 2) * (TX + 2)];
    __shared__ float2 sdisp[(TY + 2) * (TX + 2)];

    const int h = sa.h, w = sa.w;
    const float* __restrict__ disp = sa.disp;
    const float* __restrict__ lpy = sa.lp;
    const float* __restrict__ rpy = sa.rp;
    float* acc = accbase + sa.accoff;

    const int tileX = t % sa.nx;
    int t2 = t / sa.nx;
    const int tileY = t2 % sa.ny;
    const int b = t2 / sa.ny;

    const int xo0 = tileX * TX;
    const int yo0 = tileY * TY;
    const int tid = threadIdx.x;
    const float Wm1 = (float)(w - 1);
    const float invWm1 = 1.f / Wm1;

    const float* dl_base = disp + ((long long)b * 2 + 0) * h * w;
    const float* dr_base = disp + ((long long)b * 2 + 1) * h * w;

    for (int i = tid; i < (TY + 2) * (TX + 2); i += 256) {
        int sx = i % (TX + 2);
        int sy = i / (TX + 2);
        int x = min(max(xo0 - 1 + sx, 0), w - 1);
        int y = min(max(yo0 - 1 + sy, 0), h - 1);
        const float* dl_row = dl_base + (long long)y * w;
        const float* dr_row = dr_base + (long long)y * w;
        float dl = dl_row[x], dr = dr_row[x];
        sdisp[i] = make_float2(dl, dr);
        float xb = (float)x * invWm1;
        int i0L, i1L; float w0L, w1L;
        warp_coeffs((xb - dl) * Wm1, w, i0L, i1L, w0L, w1L);
        int i0R, i1R; float w0R, w1R;
        warp_coeffs((xb + dr) * Wm1, w, i0R, i1R, w0R, w1R);
#pragma unroll
        for (int c = 0; c < 3; ++c) {
            const float* lrow = lpy + (((long long)b * 3 + c) * h + y) * w;
            const float* rrow = rpy + (((long long)b * 3 + c) * h + y) * w;
            float lv = lrow[x], rv = rrow[x];
            float le = rrow[i0L] * w0L + rrow[i1L] * w1L;
            float re = lrow[i0R] * w0R + lrow[i1R] * w1R;
            simg[c][i] = make_float4(le, re, lv, rv);   // (est_pair, val_pair)
        }
    }
    __syncthreads();

    float sums[8] = {0.f, 0.f, 0.f, 0.f, 0.f, 0.f, 0.f, 0.f};
    const int tx = tid % TX, ty = tid / TX;
    const int x = xo0 + tx, y = yo0 + ty;
    if (x < w && y < h) {
        const int s = (ty + 1) * (TX + 2) + (tx + 1);
        float2 dd = sdisp[s];
        float dl = dd.x, dr = dd.y;
#pragma unroll
        for (int c = 0; c < 3; ++c) {
            float4 v = simg[c][s];
            float2 d = f2abs(make_float2(v.x, v.y) - make_float2(v.z, v.w));
            sums[0] += d.x;
            sums[1] += d.y;
        }
        {
            float xb = (float)x * invWm1;
            int i0, i1; float w0, w1;
            warp_coeffs((xb - dl) * Wm1, w, i0, i1, w0, w1);
            const float* dr_row = dr_base + (long long)y * w;
            float rl = dr_row[i0] * w0 + dr_row[i1] * w1;
            sums[2] += fabsf(rl - dl);
            warp_coeffs((xb + dr) * Wm1, w, i0, i1, w0, w1);
            const float* dl_row = dl_base + (long long)y * w;
            float lr = dl_row[i0] * w0 + dl_row[i1] * w1;
            sums[3] += fabsf(lr - dr);
        }
        const float third = 1.f / 3.f;
        if (x < w - 1) {
            float2 d1 = sdisp[s + 1];
            float2 alr = f2(0.f);
#pragma unroll
            for (int c = 0; c < 3; ++c) {
                float4 v = simg[c][s];
                float4 v1 = simg[c][s + 1];
                alr = alr + f2abs(make_float2(v.z, v.w) - make_float2(v1.z, v1.w));
            }
            sums[4] += fabsf((dl - d1.x) * expf(-alr.x * third)) +
                       fabsf((dr - d1.y) * expf(-alr.y * third));
        }
        if (y < h - 1) {
            float2 d1 = sdisp[s + (TX + 2)];
            float2 alr = f2(0.f);
#pragma unroll
            for (int c = 0; c < 3; ++c) {
                float4 v = simg[c][s];
                float4 v1 = simg[c][s + (TX + 2)];
                alr = alr + f2abs(make_float2(v.z, v.w) - make_float2(v1.z, v1.w));
            }
            sums[5] += fabsf((dl - d1.x) * expf(-alr.x * third)) +
                       fabsf((dr - d1.y) * expf(-alr.y * third));
        }
        if (x >= 1 && x <= w - 2 && y >= 1 && y <= h - 2) {
            const float2 inv9 = f2(1.f / 9.f);
            const float2 c1 = f2(C1F), c2 = f2(C2F);
            const float2 two = f2(2.f), one = f2(1.f), half_ = f2(0.5f);
#pragma unroll 1
            for (int c = 0; c < 3; ++c) {
                float2 sX = f2(0.f), sY = f2(0.f);
                float2 sXX = f2(0.f), sYY = f2(0.f), sXY = f2(0.f);
#pragma unroll
                for (int dy = 0; dy < 3; ++dy) {
#pragma unroll
                    for (int dx = 0; dx < 3; ++dx) {
                        float4 v = simg[c][(ty + dy) * (TX + 2) + (tx + dx)];
                        float2 a = make_float2(v.x, v.y);
                        float2 bb = make_float2(v.z, v.w);
                        sX = sX + a;
                        sY = sY + bb;
                        sXX = sXX + a * a;
                        sYY = sYY + bb * bb;
                        sXY = sXY + a * bb;
                    }
                }
                float2 mx = sX * inv9, my = sY * inv9;
                float2 vx = sXX * inv9 - mx * mx;
                float2 vy = sYY * inv9 - my * my;
                float2 vxy = sXY * inv9 - mx * my;
                float2 num = (two * mx * my + c1) * (two * vxy + c2);
                float2 den = (mx * mx + my * my + c1) * (vx + vy + c2);
                float2 ss = make_float2(num.x / den.x, num.y / den.y);
                float2 v = (one - ss) * half_;
                sums[6] += fminf(fmaxf(v.x, 0.f), 1.f);
                sums[7] += fminf(fmaxf(v.y, 0.f), 1.f);
            }
        }
    }
    block_acc<8>(sums, accbase + sa.accoff - sa.accoff + sa.accoff);  // == acc
    (void)acc;
}

// ---- Kernel A: scale-0 fused tiles + pyramid resize (independent work,
// co-scheduled in one launch; resize blocks dispatched last to drain tail) ----
__global__ void __launch_bounds__(256, 4)
k_fused0_resize(ScaleArgs s0, float* __restrict__ accbase,
                const float* __restrict__ left, const float* __restrict__ right,
                float* __restrict__ lo1, float* __restrict__ ro1,
                float* __restrict__ lo2, float* __restrict__ ro2,
                float* __restrict__ lo3, float* __restrict__ ro3,
                int B, int H, int W,
                int nFusedBlocks, long long n1, long long n2, long long n3) {
    if ((int)blockIdx.x < nFusedBlocks) {
        fused_tile(s0, blockIdx.x, accbase);
        return;
    }
    // resize path
    long long idx = (long long)(blockIdx.x - nFusedBlocks) * blockDim.x + threadIdx.x;
    int oh, ow;
    float* lo;
    float* ro;
    if (idx < n1) {
        oh = H / 2; ow = W / 2; lo = lo1; ro = ro1;
    } else if (idx < n1 + n2) {
        idx -= n1; oh = H / 4; ow = W / 4; lo = lo2; ro = ro2;
    } else if (idx < n1 + n2 + n3) {
        idx -= n1 + n2; oh = H / 8; ow = W / 8; lo = lo3; ro = ro3;
    } else {
        return;
    }
    long long half = (long long)B * 3 * oh * ow;
    const float* src = left;
    float* dst = lo;
    if (idx >= half) { src = right; dst = ro; idx -= half; }
    int x = (int)(idx % ow);
    long long t = idx / ow;
    int y = (int)(t % oh);
    t /= oh;
    int c = (int)(t % 3);
    int b = (int)(t / 3);
    float sy = (float)(H - 1) / (float)(oh - 1);
    float sx = (float)(W - 1) / (float)(ow - 1);
    float fy = y * sy;
    float fx = x * sx;
    int y0 = (int)floorf(fy); float wy = fy - (float)y0;
    int x0 = (int)floorf(fx); float wx = fx - (float)x0;
    int y1 = min(y0 + 1, H - 1); y0 = min(y0, H - 1);
    int x1 = min(x0 + 1, W - 1); x0 = min(x0, W - 1);
    const float* p = src + (((long long)b * 3 + c) * H) * W;
    float a00 = p[(long long)y0 * W + x0];
    float a10 = p[(long long)y1 * W + x0];
    float a01 = p[(long long)y0 * W + x1];
    float a11 = p[(long long)y1 * W + x1];
    float r0 = a00 * (1.f - wy) + a10 * wy;
    float r1 = a01 * (1.f - wy) + a11 * wy;
    dst[(((long long)b * 3 + c) * oh + y) * ow + x] = r0 * (1.f - wx) + r1 * wx;
}

// ---- Kernel B: scales 1-3 fused (needs pyramid from kernel A) ----
__global__ void __launch_bounds__(256, 4)
k_fused_small(ScaleArgs s1, ScaleArgs s2, ScaleArgs s3,
              float* __restrict__ accbase) {
    ScaleArgs sa;
    {
        int blk = blockIdx.x;
        if (blk >= s3.blk0)      sa = s3;
        else if (blk >= s2.blk0) sa = s2;
        else                     sa = s1;
    }
    fused_tile(sa, blockIdx.x - sa.blk0, accbase);
}

__global__ void k_final(const float* __restrict__ acc, float* __restrict__ out,
                        int B, int H, int W) {
    if (threadIdx.x != 0 || blockIdx.x != 0) return;
    float img = 0.f, lr = 0.f, sm = 0.f;
    for (int i = 0; i < 4; ++i) {
        int r = 1 << i;
        int h = H / r, w = W / r;
        const float* a = acc + i * 8;
        float Nl1 = (float)B * 3.f * (float)h * (float)w;
        float Nss = (float)B * 3.f * (float)(h - 2) * (float)(w - 2);
        float Nlr = (float)B * (float)h * (float)w;
        float Nsx = (float)B * (float)h * (float)(w - 1);
        float Nsy = (float)B * (float)(h - 1) * (float)w;
        img += 0.5f * (a[6] / Nss) + 0.5f * (a[0] / Nl1)
             + 0.5f * (a[7] / Nss) + 0.5f * (a[1] / Nl1);
        lr += a[2] / Nlr + a[3] / Nlr;
        sm += (a[4] / Nsx + a[5] / Nsy) / (float)r;
    }
    out[0] = img + 0.1f * sm + 1.0f * lr;
}

extern "C" void kernel_launch(void* const* d_in, const int* in_sizes, int n_in,
                              void* d_out, int out_size, void* d_ws, size_t ws_size,
                              hipStream_t stream) {
    const int B = 16, H = 384, W = 768;
    const float* disp[4] = {(const float*)d_in[0], (const float*)d_in[1],
                            (const float*)d_in[2], (const float*)d_in[3]};
    const float* left = (const float*)d_in[4];
    const float* right = (const float*)d_in[5];
    float* out = (float*)d_out;

    float* acc = (float*)d_ws;
    float* pyr = acc + 256;
    long long sz1 = (long long)B * 3 * (H / 2) * (W / 2);
    long long sz2 = (long long)B * 3 * (H / 4) * (W / 4);
    long long sz3 = (long long)B * 3 * (H / 8) * (W / 8);
    float* lp1 = pyr;
    float* rp1 = lp1 + sz1;
    float* lp2 = rp1 + sz1;
    float* rp2 = lp2 + sz2;
    float* lp3 = rp2 + sz2;
    float* rp3 = lp3 + sz3;

    const int TB = 256;
    const float* lp[4] = {left, lp1, lp2, lp3};
    const float* rp[4] = {right, rp1, rp2, rp3};
    ScaleArgs sa[4];
    for (int i = 0; i < 4; ++i) {
        int r = 1 << i;
        int h = H / r, w = W / r;
        sa[i].disp = disp[i];
        sa[i].lp = lp[i];
        sa[i].rp = rp[i];
        sa[i].h = h;
        sa[i].w = w;
        sa[i].nx = w / TX;
        sa[i].ny = h / TY;
        sa[i].accoff = i * 8;
        sa[i].blk0 = 0;
    }

    hipLaunchKernelGGL(k_zero, dim3(1), dim3(64), 0, stream, acc);

    // Kernel A: scale-0 fused + all resize work
    {
        int nFused = sa[0].nx * sa[0].ny * B;
        long long n1 = 2 * sz1, n2 = 2 * sz2, n3 = 2 * sz3;
        long long nrElem = n1 + n2 + n3;
        int nResize = (int)((nrElem + TB - 1) / TB);
        hipLaunchKernelGGL(k_fused0_resize, dim3((unsigned)(nFused + nResize)), dim3(TB), 0, stream,
                           sa[0], acc, left, right, lp1, rp1, lp2, rp2, lp3, rp3,
                           B, H, W, nFused, n1, n2, n3);
    }

    // Kernel B: scales 1-3 fused
    {
        int b1 = sa[1].nx * sa[1].ny * B;
        int b2 = sa[2].nx * sa[2].ny * B;
        int b3 = sa[3].nx * sa[3].ny * B;
        sa[1].blk0 = 0;
        sa[2].blk0 = b1;
        sa[3].blk0 = b1 + b2;
        hipLaunchKernelGGL(k_fused_small, dim3((unsigned)(b1 + b2 + b3)), dim3(TB), 0, stream,
                           sa[1], sa[2], sa[3], acc);
    }
    hipLaunchKernelGGL(k_final, dim3(1), dim3(64), 0, stream, acc, out, B, H, W);
}

// Round 8
// 504.887 us; speedup vs baseline: 1.0740x; 1.0180x over previous
//
#include <hip/hip_runtime.h>
#include <math.h>

#define C1F 1.0e-4f   // 0.01^2
#define C2F 9.0e-4f   // 0.03^2
#define TX 32
#define TY 8

// acc layout: per scale i (0..3), base = i*8
//  +0: sum |left_est - lpy|      +1: sum |right_est - rpy|
//  +2: sum |rl_disp - dl|        +3: sum |lr_disp - dr|
//  +4: sum x-grad smooth (dl+dr) +5: sum y-grad smooth (dl+dr)
//  +6: sum ssim_l (clipped)      +7: sum ssim_r

struct ScaleArgs {
    const float* disp;
    const float* lp;
    const float* rp;
    int h, w, nx, ny, blk0, accoff;
};

__device__ __forceinline__ float2 f2(float v) { return make_float2(v, v); }
__device__ __forceinline__ float2 f2abs(float2 a) {
    return make_float2(fabsf(a.x), fabsf(a.y));
}

__device__ __forceinline__ void warp_coeffs(float px, int W, int& i0, int& i1,
                                            float& w0, float& w1) {
    float x0f = floorf(px);
    float f = px - x0f;
    int x0i = (int)x0f;
    int x1i = x0i + 1;
    float v0 = (x0i >= 0 && x0i < W) ? 1.f : 0.f;
    float v1 = (x1i >= 0 && x1i < W) ? 1.f : 0.f;
    i0 = min(max(x0i, 0), W - 1);
    i1 = min(max(x1i, 0), W - 1);
    w0 = v0 * (1.f - f);
    w1 = v1 * f;
}

template<int N>
__device__ __forceinline__ void block_acc(const float* vals, float* gacc) {
    __shared__ float sacc[N];
    if (threadIdx.x < N) sacc[threadIdx.x] = 0.f;
    __syncthreads();
#pragma unroll
    for (int k = 0; k < N; ++k) {
        float v = vals[k];
#pragma unroll
        for (int off = 32; off > 0; off >>= 1) v += __shfl_down(v, off, 64);
        if ((threadIdx.x & 63) == 0) atomicAdd(&sacc[k], v);
    }
    __syncthreads();
    if (threadIdx.x < N) atomicAdd(&gacc[threadIdx.x], sacc[threadIdx.x]);
}

__global__ void k_zero(float* acc) {
    if (threadIdx.x < 64) acc[threadIdx.x] = 0.f;
}

// ---- fused loss tile: phase-split staging for max outstanding loads,
// int32 offset arithmetic, fast rcp/exp (threshold 6.4e-2 >> 1e-5 shift) ----
__device__ __forceinline__ void fused_tile(const ScaleArgs& sa, int t,
                                           float* __restrict__ accbase) {
    __shared__ float4 simg[3][(TY + 2) * (TX + 2)];
    __shared__ float2 sdisp[(TY + 2) * (TX + 2)];

    const int h = sa.h, w = sa.w;
    float* acc = accbase + sa.accoff;

    const int tileX = t % sa.nx;
    int t2 = t / sa.nx;
    const int tileY = t2 % sa.ny;
    const int b = t2 / sa.ny;

    const int xo0 = tileX * TX;
    const int yo0 = tileY * TY;
    const int tid = threadIdx.x;
    const float Wm1 = (float)(w - 1);
    const float invWm1 = 1.f / Wm1;
    const int chs = h * w;

    const float* __restrict__ dl_base = sa.disp + (b * 2 + 0) * chs;
    const float* __restrict__ dr_base = sa.disp + (b * 2 + 1) * chs;
    const float* __restrict__ limg = sa.lp + b * 3 * chs;
    const float* __restrict__ rimg = sa.rp + b * 3 * chs;

    // ---- staging: 2 slots/thread, phase-split so all loads are in flight ----
    const int NS = (TY + 2) * (TX + 2);           // 340
    const int nk = (tid + 256 < NS) ? 2 : 1;      // tid < 256 <= NS always
    int xs[2], ys[2];
    float dlv[2], drv[2];
#pragma unroll
    for (int k = 0; k < 2; ++k) {
        if (k < nk) {
            int i = tid + k * 256;
            int sx = i % (TX + 2);
            int sy = i / (TX + 2);
            int x = min(max(xo0 - 1 + sx, 0), w - 1);
            int y = min(max(yo0 - 1 + sy, 0), h - 1);
            xs[k] = x; ys[k] = y;
            int off = y * w + x;
            dlv[k] = dl_base[off];
            drv[k] = dr_base[off];
        }
    }
    int i0L[2], i1L[2], i0R[2], i1R[2];
    float w0L[2], w1L[2], w0R[2], w1R[2];
    float lvv[2][3], rvv[2][3], gr0[2][3], gr1[2][3], gl0[2][3], gl1[2][3];
#pragma unroll
    for (int k = 0; k < 2; ++k) {
        if (k < nk) {
            float xb = (float)xs[k] * invWm1;
            warp_coeffs((xb - dlv[k]) * Wm1, w, i0L[k], i1L[k], w0L[k], w1L[k]);
            warp_coeffs((xb + drv[k]) * Wm1, w, i0R[k], i1R[k], w0R[k], w1R[k]);
            int rowoff = ys[k] * w;
#pragma unroll
            for (int c = 0; c < 3; ++c) {
                int co = c * chs + rowoff;
                lvv[k][c] = limg[co + xs[k]];
                rvv[k][c] = rimg[co + xs[k]];
                gr0[k][c] = rimg[co + i0L[k]];
                gr1[k][c] = rimg[co + i1L[k]];
                gl0[k][c] = limg[co + i0R[k]];
                gl1[k][c] = limg[co + i1R[k]];
            }
        }
    }
#pragma unroll
    for (int k = 0; k < 2; ++k) {
        if (k < nk) {
            int i = tid + k * 256;
            sdisp[i] = make_float2(dlv[k], drv[k]);
#pragma unroll
            for (int c = 0; c < 3; ++c) {
                float le = gr0[k][c] * w0L[k] + gr1[k][c] * w1L[k];
                float re = gl0[k][c] * w0R[k] + gl1[k][c] * w1R[k];
                simg[c][i] = make_float4(le, re, lvv[k][c], rvv[k][c]);
            }
        }
    }
    __syncthreads();

    float sums[8] = {0.f, 0.f, 0.f, 0.f, 0.f, 0.f, 0.f, 0.f};
    const int tx = tid % TX, ty = tid / TX;
    const int x = xo0 + tx, y = yo0 + ty;
    if (x < w && y < h) {
        const int s = (ty + 1) * (TX + 2) + (tx + 1);
        float2 dd = sdisp[s];
        float dl = dd.x, dr = dd.y;
#pragma unroll
        for (int c = 0; c < 3; ++c) {
            float4 v = simg[c][s];
            float2 d = f2abs(make_float2(v.x, v.y) - make_float2(v.z, v.w));
            sums[0] += d.x;
            sums[1] += d.y;
        }
        // LR consistency (far gathers on disp rows -> global)
        {
            float xb = (float)x * invWm1;
            int i0, i1; float w0, w1;
            warp_coeffs((xb - dl) * Wm1, w, i0, i1, w0, w1);
            const float* dr_row = dr_base + y * w;
            float rl = dr_row[i0] * w0 + dr_row[i1] * w1;
            sums[2] += fabsf(rl - dl);
            warp_coeffs((xb + dr) * Wm1, w, i0, i1, w0, w1);
            const float* dl_row = dl_base + y * w;
            float lr = dl_row[i0] * w0 + dl_row[i1] * w1;
            sums[3] += fabsf(lr - dr);
        }
        const float third = 1.f / 3.f;
        if (x < w - 1) {
            float2 d1 = sdisp[s + 1];
            float2 alr = f2(0.f);
#pragma unroll
            for (int c = 0; c < 3; ++c) {
                float4 v = simg[c][s];
                float4 v1 = simg[c][s + 1];
                alr = alr + f2abs(make_float2(v.z, v.w) - make_float2(v1.z, v1.w));
            }
            sums[4] += fabsf((dl - d1.x) * __expf(-alr.x * third)) +
                       fabsf((dr - d1.y) * __expf(-alr.y * third));
        }
        if (y < h - 1) {
            float2 d1 = sdisp[s + (TX + 2)];
            float2 alr = f2(0.f);
#pragma unroll
            for (int c = 0; c < 3; ++c) {
                float4 v = simg[c][s];
                float4 v1 = simg[c][s + (TX + 2)];
                alr = alr + f2abs(make_float2(v.z, v.w) - make_float2(v1.z, v1.w));
            }
            sums[5] += fabsf((dl - d1.x) * __expf(-alr.x * third)) +
                       fabsf((dr - d1.y) * __expf(-alr.y * third));
        }
        if (x >= 1 && x <= w - 2 && y >= 1 && y <= h - 2) {
            const float2 inv9 = f2(1.f / 9.f);
            const float2 c1 = f2(C1F), c2 = f2(C2F);
            const float2 two = f2(2.f), one = f2(1.f), half_ = f2(0.5f);
#pragma unroll 1
            for (int c = 0; c < 3; ++c) {
                float2 sX = f2(0.f), sY = f2(0.f);
                float2 sXX = f2(0.f), sYY = f2(0.f), sXY = f2(0.f);
#pragma unroll
                for (int dy = 0; dy < 3; ++dy) {
#pragma unroll
                    for (int dx = 0; dx < 3; ++dx) {
                        float4 v = simg[c][(ty + dy) * (TX + 2) + (tx + dx)];
                        float2 a = make_float2(v.x, v.y);
                        float2 bb = make_float2(v.z, v.w);
                        sX = sX + a;
                        sY = sY + bb;
                        sXX = sXX + a * a;
                        sYY = sYY + bb * bb;
                        sXY = sXY + a * bb;
                    }
                }
                float2 mx = sX * inv9, my = sY * inv9;
                float2 vx = sXX * inv9 - mx * mx;
                float2 vy = sYY * inv9 - my * my;
                float2 vxy = sXY * inv9 - mx * my;
                float2 num = (two * mx * my + c1) * (two * vxy + c2);
                float2 den = (mx * mx + my * my + c1) * (vx + vy + c2);
                float2 ss = make_float2(num.x * __builtin_amdgcn_rcpf(den.x),
                                        num.y * __builtin_amdgcn_rcpf(den.y));
                float2 v = (one - ss) * half_;
                sums[6] += fminf(fmaxf(v.x, 0.f), 1.f);
                sums[7] += fminf(fmaxf(v.y, 0.f), 1.f);
            }
        }
    }
    block_acc<8>(sums, acc);
}

// ---- Kernel A: scale-0 fused tiles + pyramid resize ----
__global__ void __launch_bounds__(256, 4)
k_fused0_resize(ScaleArgs s0, float* __restrict__ accbase,
                const float* __restrict__ left, const float* __restrict__ right,
                float* __restrict__ lo1, float* __restrict__ ro1,
                float* __restrict__ lo2, float* __restrict__ ro2,
                float* __restrict__ lo3, float* __restrict__ ro3,
                int B, int H, int W,
                int nFusedBlocks, long long n1, long long n2, long long n3) {
    if ((int)blockIdx.x < nFusedBlocks) {
        fused_tile(s0, blockIdx.x, accbase);
        return;
    }
    long long idx = (long long)(blockIdx.x - nFusedBlocks) * blockDim.x + threadIdx.x;
    int oh, ow;
    float* lo;
    float* ro;
    if (idx < n1) {
        oh = H / 2; ow = W / 2; lo = lo1; ro = ro1;
    } else if (idx < n1 + n2) {
        idx -= n1; oh = H / 4; ow = W / 4; lo = lo2; ro = ro2;
    } else if (idx < n1 + n2 + n3) {
        idx -= n1 + n2; oh = H / 8; ow = W / 8; lo = lo3; ro = ro3;
    } else {
        return;
    }
    long long half = (long long)B * 3 * oh * ow;
    const float* src = left;
    float* dst = lo;
    if (idx >= half) { src = right; dst = ro; idx -= half; }
    int x = (int)(idx % ow);
    long long t = idx / ow;
    int y = (int)(t % oh);
    t /= oh;
    int c = (int)(t % 3);
    int b = (int)(t / 3);
    float sy = (float)(H - 1) / (float)(oh - 1);
    float sx = (float)(W - 1) / (float)(ow - 1);
    float fy = y * sy;
    float fx = x * sx;
    int y0 = (int)floorf(fy); float wy = fy - (float)y0;
    int x0 = (int)floorf(fx); float wx = fx - (float)x0;
    int y1 = min(y0 + 1, H - 1); y0 = min(y0, H - 1);
    int x1 = min(x0 + 1, W - 1); x0 = min(x0, W - 1);
    const float* p = src + ((long long)b * 3 + c) * H * W;
    float a00 = p[(long long)y0 * W + x0];
    float a10 = p[(long long)y1 * W + x0];
    float a01 = p[(long long)y0 * W + x1];
    float a11 = p[(long long)y1 * W + x1];
    float r0 = a00 * (1.f - wy) + a10 * wy;
    float r1 = a01 * (1.f - wy) + a11 * wy;
    dst[(((long long)b * 3 + c) * oh + y) * ow + x] = r0 * (1.f - wx) + r1 * wx;
}

// ---- Kernel B: scales 1-3 fused ----
__global__ void __launch_bounds__(256, 4)
k_fused_small(ScaleArgs s1, ScaleArgs s2, ScaleArgs s3,
              float* __restrict__ accbase) {
    ScaleArgs sa;
    {
        int blk = blockIdx.x;
        if (blk >= s3.blk0)      sa = s3;
        else if (blk >= s2.blk0) sa = s2;
        else                     sa = s1;
    }
    fused_tile(sa, blockIdx.x - sa.blk0, accbase);
}

__global__ void k_final(const float* __restrict__ acc, float* __restrict__ out,
                        int B, int H, int W) {
    if (threadIdx.x != 0 || blockIdx.x != 0) return;
    float img = 0.f, lr = 0.f, sm = 0.f;
    for (int i = 0; i < 4; ++i) {
        int r = 1 << i;
        int h = H / r, w = W / r;
        const float* a = acc + i * 8;
        float Nl1 = (float)B * 3.f * (float)h * (float)w;
        float Nss = (float)B * 3.f * (float)(h - 2) * (float)(w - 2);
        float Nlr = (float)B * (float)h * (float)w;
        float Nsx = (float)B * (float)h * (float)(w - 1);
        float Nsy = (float)B * (float)(h - 1) * (float)w;
        img += 0.5f * (a[6] / Nss) + 0.5f * (a[0] / Nl1)
             + 0.5f * (a[7] / Nss) + 0.5f * (a[1] / Nl1);
        lr += a[2] / Nlr + a[3] / Nlr;
        sm += (a[4] / Nsx + a[5] / Nsy) / (float)r;
    }
    out[0] = img + 0.1f * sm + 1.0f * lr;
}

extern "C" void kernel_launch(void* const* d_in, const int* in_sizes, int n_in,
                              void* d_out, int out_size, void* d_ws, size_t ws_size,
                              hipStream_t stream) {
    const int B = 16, H = 384, W = 768;
    const float* disp[4] = {(const float*)d_in[0], (const float*)d_in[1],
                            (const float*)d_in[2], (const float*)d_in[3]};
    const float* left = (const float*)d_in[4];
    const float* right = (const float*)d_in[5];
    float* out = (float*)d_out;

    float* acc = (float*)d_ws;
    float* pyr = acc + 256;
    long long sz1 = (long long)B * 3 * (H / 2) * (W / 2);
    long long sz2 = (long long)B * 3 * (H / 4) * (W / 4);
    long long sz3 = (long long)B * 3 * (H / 8) * (W / 8);
    float* lp1 = pyr;
    float* rp1 = lp1 + sz1;
    float* lp2 = rp1 + sz1;
    float* rp2 = lp2 + sz2;
    float* lp3 = rp2 + sz2;
    float* rp3 = lp3 + sz3;

    const int TB = 256;
    const float* lp[4] = {left, lp1, lp2, lp3};
    const float* rp[4] = {right, rp1, rp2, rp3};
    ScaleArgs sa[4];
    for (int i = 0; i < 4; ++i) {
        int r = 1 << i;
        int h = H / r, w = W / r;
        sa[i].disp = disp[i];
        sa[i].lp = lp[i];
        sa[i].rp = rp[i];
        sa[i].h = h;
        sa[i].w = w;
        sa[i].nx = w / TX;
        sa[i].ny = h / TY;
        sa[i].accoff = i * 8;
        sa[i].blk0 = 0;
    }

    hipLaunchKernelGGL(k_zero, dim3(1), dim3(64), 0, stream, acc);

    // Kernel A: scale-0 fused + all resize work
    {
        int nFused = sa[0].nx * sa[0].ny * B;
        long long n1 = 2 * sz1, n2 = 2 * sz2, n3 = 2 * sz3;
        long long nrElem = n1 + n2 + n3;
        int nResize = (int)((nrElem + TB - 1) / TB);
        hipLaunchKernelGGL(k_fused0_resize, dim3((unsigned)(nFused + nResize)), dim3(TB), 0, stream,
                           sa[0], acc, left, right, lp1, rp1, lp2, rp2, lp3, rp3,
                           B, H, W, nFused, n1, n2, n3);
    }

    // Kernel B: scales 1-3 fused
    {
        int b1 = sa[1].nx * sa[1].ny * B;
        int b2 = sa[2].nx * sa[2].ny * B;
        int b3 = sa[3].nx * sa[3].ny * B;
        sa[1].blk0 = 0;
        sa[2].blk0 = b1;
        sa[3].blk0 = b1 + b2;
        hipLaunchKernelGGL(k_fused_small, dim3((unsigned)(b1 + b2 + b3)), dim3(TB), 0, stream,
                           sa[1], sa[2], sa[3], acc);
    }
    hipLaunchKernelGGL(k_final, dim3(1), dim3(64), 0, stream, acc, out, B, H, W);
}